// Round 4
// baseline (426.858 us; speedup 1.0000x reference)
//
#include <hip/hip_runtime.h>
#include <hip/hip_bf16.h>
#include <math.h>

#define B_ 4
#define F_ 256
#define H_ 64
#define W_ 64
#define C_ 19
#define S_ 256
#define N_ (B_*H_*W_)      // 16384 pixels
#define M_ (C_*2*S_)       // 9728 memory rows

typedef __bf16 bf16_t;
typedef bf16_t bf16x8 __attribute__((ext_vector_type(8)));
typedef float floatx4 __attribute__((ext_vector_type(4)));

#define AS1 __attribute__((address_space(1)))
#define AS3 __attribute__((address_space(3)))

#define ZERO_FLOATS (N_ + 2*C_)

// ---------------- kernel 1: fused prep ----------------
__global__ __launch_bounds__(256) void k_prep(const float* __restrict__ pred,
                                              const float* __restrict__ mem,
                                              __hip_bfloat16* __restrict__ A16,
                                              __hip_bfloat16* __restrict__ B16,
                                              float* __restrict__ zero_base) {
    int bid = blockIdx.x;
    int t = threadIdx.x;
    if (bid < 256) {
        // ---- conv A: block = (b, hw-tile of 64); thread (q = t>>6, j = t&63)
        __shared__ float part[4][64];
        __shared__ float invf_s[64];
        int b = bid >> 6, hw0 = (bid & 63) * 64;
        int j = t & 63, q = t >> 6;
        const float* base = pred + ((size_t)b * F_ + q * 64) * 4096 + hw0 + j;
        float v[64];
        float s = 0.f;
        #pragma unroll
        for (int i = 0; i < 64; ++i) {
            float x = base[(size_t)i * 4096];
            v[i] = x;
            s += x * x;
        }
        part[q][j] = s;
        __syncthreads();
        if (t < 64) invf_s[t] = 1.0f / sqrtf(part[0][t] + part[1][t] + part[2][t] + part[3][t]);
        __syncthreads();
        float invf = invf_s[j];
        __hip_bfloat16* dst = A16 + (size_t)(b * 4096 + hw0 + j) * F_ + q * 64;
        #pragma unroll
        for (int c = 0; c < 8; ++c) {
            __hip_bfloat16 tmp[8];
            #pragma unroll
            for (int u = 0; u < 8; ++u) tmp[u] = __float2bfloat16(v[c * 8 + u] * invf);
            *(float4*)&dst[c * 8] = *(float4*)tmp;
        }
    } else if (bid < 256 + M_ / 4) {
        // ---- conv B: wave per memory row
        int row  = (bid - 256) * 4 + (t >> 6);
        int lane = t & 63;
        float4 a = ((const float4*)(mem + (size_t)row * F_))[lane];
        float s = a.x*a.x + a.y*a.y + a.z*a.z + a.w*a.w;
        #pragma unroll
        for (int off = 32; off; off >>= 1) s += __shfl_xor(s, off, 64);
        float invm = 1.0f / sqrtf(s);
        __hip_bfloat16 tmp[4];
        tmp[0] = __float2bfloat16(a.x * invm);
        tmp[1] = __float2bfloat16(a.y * invm);
        tmp[2] = __float2bfloat16(a.z * invm);
        tmp[3] = __float2bfloat16(a.w * invm);
        *(float2*)&B16[(size_t)row * F_ + lane * 4] = *(float2*)tmp;
    } else {
        int idx = (bid - (256 + M_ / 4)) * 1024 + t * 4;
        #pragma unroll
        for (int u = 0; u < 4; ++u)
            if (idx + u < ZERO_FLOATS) zero_base[idx + u] = 0.f;
    }
}

// ---------------- kernel 2: MFMA cos->exp GEMM, double-buffered BK=32 ----------------
// grid = (M_/128=76, N_/128=128), block = 256 (4 waves), each wave a 64x64 quadrant.
// LDS: per operand 2 buffers of 8 sub-blocks x 1KB. Sub-block sb = 16-row group.
// Within sub-block, byte order = lane*16 with lane = (kchunk<<4)|row, so the
// fragment ds_read_b128 at base+lane*16 is contiguous (zero conflicts) and
// global_load_lds staging writes the identical order.
__global__ __launch_bounds__(256) void k_mfma(const __hip_bfloat16* __restrict__ A16,
                                              const __hip_bfloat16* __restrict__ B16,
                                              const int* __restrict__ labels,
                                              float* __restrict__ total,
                                              float* __restrict__ classbuf) {
    __shared__ __hip_bfloat16 As[2][128 * 32];   // 2 x 8 KB
    __shared__ __hip_bfloat16 Bs[2][128 * 32];   // 2 x 8 KB
    __shared__ int lab_s[128];

    int t = threadIdx.x;
    int w = t >> 6, lane = t & 63;
    int m0 = blockIdx.x * 128;
    int n0 = blockIdx.y * 128;
    if (t < 128) lab_s[t] = labels[n0 + t];

    int nq = (w & 1) * 64, mq = (w >> 1) * 64;
    floatx4 acc[4][4];
    #pragma unroll
    for (int i = 0; i < 4; ++i)
        #pragma unroll
        for (int j = 0; j < 4; ++j) acc[i][j] = (floatx4){0.f, 0.f, 0.f, 0.f};

    int rowl = lane & 15;
    int kch  = lane >> 4;
    int kk   = kch * 8;

    // wave w stages sub-blocks {w, w+4} of A and B into buffer bf
    int sb0 = w,     row0 = sb0 * 16 + rowl;
    int sb1 = w + 4, row1 = sb1 * 16 + rowl;
    const __hip_bfloat16* gA0 = A16 + (size_t)(n0 + row0) * F_ + kk;
    const __hip_bfloat16* gA1 = A16 + (size_t)(n0 + row1) * F_ + kk;
    const __hip_bfloat16* gB0 = B16 + (size_t)(m0 + row0) * F_ + kk;
    const __hip_bfloat16* gB1 = B16 + (size_t)(m0 + row1) * F_ + kk;

#define STAGE(it, bf)                                                                   \
    do {                                                                                \
        int _k0 = (it) * 32;                                                            \
        __builtin_amdgcn_global_load_lds((const AS1 unsigned int*)(gA0 + _k0),          \
                                         (AS3 unsigned int*)&As[bf][sb0 * 512], 16, 0, 0); \
        __builtin_amdgcn_global_load_lds((const AS1 unsigned int*)(gB0 + _k0),          \
                                         (AS3 unsigned int*)&Bs[bf][sb0 * 512], 16, 0, 0); \
        __builtin_amdgcn_global_load_lds((const AS1 unsigned int*)(gA1 + _k0),          \
                                         (AS3 unsigned int*)&As[bf][sb1 * 512], 16, 0, 0); \
        __builtin_amdgcn_global_load_lds((const AS1 unsigned int*)(gB1 + _k0),          \
                                         (AS3 unsigned int*)&Bs[bf][sb1 * 512], 16, 0, 0); \
    } while (0)

    STAGE(0, 0);
    __syncthreads();
    #pragma unroll
    for (int it = 0; it < 8; ++it) {
        int bf = it & 1;
        if (it < 7) STAGE(it + 1, bf ^ 1);      // prefetch next tile, no wait
        bf16x8 af[4], bfr[4];
        #pragma unroll
        for (int ni = 0; ni < 4; ++ni)
            af[ni] = *(const bf16x8*)&As[bf][((w & 1) * 4 + ni) * 512 + lane * 8];
        #pragma unroll
        for (int mi = 0; mi < 4; ++mi)
            bfr[mi] = *(const bf16x8*)&Bs[bf][((w >> 1) * 4 + mi) * 512 + lane * 8];
        #pragma unroll
        for (int ni = 0; ni < 4; ++ni)
            #pragma unroll
            for (int mi = 0; mi < 4; ++mi)
                acc[ni][mi] = __builtin_amdgcn_mfma_f32_16x16x32_bf16(af[ni], bfr[mi], acc[ni][mi], 0, 0, 0);
        __syncthreads();                         // next buffer staged; frag reads done
    }
#undef STAGE

    // epilogue: E = exp(2*cos); row sums -> total (atomic); own-class scatter
    int cls   = m0 >> 9;
    int mbase = (m0 & 511) + mq;
    int colL  = lane & 15;
    int rgrp  = (lane >> 4) * 4;
    #pragma unroll
    for (int ni = 0; ni < 4; ++ni) {
        float Ev[4][4];
        float rsum[4] = {0.f, 0.f, 0.f, 0.f};
        #pragma unroll
        for (int mi = 0; mi < 4; ++mi)
            #pragma unroll
            for (int r = 0; r < 4; ++r) {
                float e = __expf(2.0f * acc[ni][mi][r]);
                Ev[mi][r] = e;
                rsum[r] += e;
            }
        #pragma unroll
        for (int r = 0; r < 4; ++r) {
            float s = rsum[r];
            s += __shfl_xor(s, 1, 64);
            s += __shfl_xor(s, 2, 64);
            s += __shfl_xor(s, 4, 64);
            s += __shfl_xor(s, 8, 64);
            int nrow = nq + ni * 16 + rgrp + r;
            if (colL == 0) atomicAdd(&total[n0 + nrow], s);
            if (lab_s[nrow] == cls) {
                size_t base = (size_t)(n0 + nrow) * 512 + mbase;
                #pragma unroll
                for (int mi = 0; mi < 4; ++mi)
                    classbuf[base + mi * 16 + colL] = Ev[mi][r];
            }
        }
    }
}

// ---------------- kernel 3: per-pixel log terms -> termbuf (no atomics) ----------------
__global__ __launch_bounds__(256) void k_terms(const float* __restrict__ classbuf,
                                               const float* __restrict__ total,
                                               const int*   __restrict__ mask,
                                               const int*   __restrict__ wmem,
                                               float* __restrict__ termbuf) {
    int wid  = threadIdx.x >> 6;
    int lane = threadIdx.x & 63;
    int n = blockIdx.x * 4 + wid;
    if (!mask[n]) {
        if (lane == 0) termbuf[n] = 0.f;
        return;
    }
    int wm = wmem[n];
    const float4* p = (const float4*)&classbuf[(size_t)n * 512];
    float4 v0 = p[lane * 2];
    float4 v1 = p[lane * 2 + 1];
    float s = v0.x + v0.y + v0.z + v0.w + v1.x + v1.y + v1.z + v1.w;
    #pragma unroll
    for (int off = 1; off < 64; off <<= 1) s += __shfl_xor(s, off, 64);
    float down = total[n] - s;
    int lo = (wm == 1) ? 0 : 32;                // wm==1 -> first half [0,S)
    float ts = 0.f;
    if (lane >= lo && lane < lo + 32) {
        float vv[8] = {v0.x, v0.y, v0.z, v0.w, v1.x, v1.y, v1.z, v1.w};
        #pragma unroll
        for (int q = 0; q < 8; ++q) {
            float pv = vv[q];
            ts += -logf(pv / (pv + down + 1e-12f) + 1e-12f);
        }
    }
    #pragma unroll
    for (int off = 1; off < 64; off <<= 1) ts += __shfl_xor(ts, off, 64);
    if (lane == 0) termbuf[n] = ts;
}

// ---------------- kernel 4: per-class reduction (block per class, no atomics) ----
__global__ __launch_bounds__(256) void k_reduce(const float* __restrict__ termbuf,
                                                const int*   __restrict__ labels,
                                                const int*   __restrict__ mask,
                                                float* __restrict__ class_sum,
                                                int*   __restrict__ class_cnt) {
    int c = blockIdx.x;
    int t = threadIdx.x;
    float s = 0.f;
    int cnt = 0;
    for (int n = t; n < N_; n += 256) {
        bool sel = mask[n] && (labels[n] == c);
        if (sel) { s += termbuf[n]; ++cnt; }
    }
    __shared__ float sred[256];
    __shared__ int   cred[256];
    sred[t] = s; cred[t] = cnt;
    __syncthreads();
    #pragma unroll
    for (int off = 128; off; off >>= 1) {
        if (t < off) { sred[t] += sred[t + off]; cred[t] += cred[t + off]; }
        __syncthreads();
    }
    if (t == 0) { class_sum[c] = sred[0]; class_cnt[c] = cred[0]; }
}

// ---------------- kernel 5: final class average ----------------
__global__ void k_final(const float* __restrict__ class_sum,
                        const int*   __restrict__ class_cnt,
                        float* __restrict__ out) {
    if (threadIdx.x == 0 && blockIdx.x == 0) {
        float loss = 0.f, kc = 0.f;
        for (int c = 0; c < C_; ++c) {
            int cnt = class_cnt[c];
            if (cnt > 0) {
                loss += class_sum[c] / ((float)cnt * (float)S_);
                kc += 1.f;
            }
        }
        out[0] = loss / fmaxf(kc, 1.f);
    }
}

extern "C" void kernel_launch(void* const* d_in, const int* in_sizes, int n_in,
                              void* d_out, int out_size, void* d_ws, size_t ws_size,
                              hipStream_t stream) {
    const float* mem    = (const float*)d_in[0];
    const float* pred   = (const float*)d_in[1];
    const int*   labels = (const int*)  d_in[2];
    const int*   mask   = (const int*)  d_in[3];
    const int*   wmem   = (const int*)  d_in[4];
    float* out = (float*)d_out;

    float* ws        = (float*)d_ws;
    float* total     = ws;                        // N_ floats (zeroed by k_prep)
    float* class_sum = ws + N_;                   // C_ floats
    int*   class_cnt = (int*)(ws + N_ + C_);      // C_ ints
    float* termbuf   = ws + 16432;                // N_ floats
    float* classbuf  = ws + 32816;                // N_*512 floats = 33.5 MB (16B aligned)
    __hip_bfloat16* A16 = (__hip_bfloat16*)(ws + 32816 + (size_t)N_ * 512);            // 8 MB
    __hip_bfloat16* B16 = (__hip_bfloat16*)(ws + 32816 + (size_t)N_ * 512 + 2097152);  // 4.75 MB

    k_prep<<<256 + M_ / 4 + 17, 256, 0, stream>>>(pred, mem, A16, B16, ws);

    dim3 g2(M_ / 128, N_ / 128);
    k_mfma<<<g2, 256, 0, stream>>>(A16, B16, labels, total, classbuf);

    k_terms<<<N_ / 4, 256, 0, stream>>>(classbuf, total, mask, wmem, termbuf);
    k_reduce<<<C_, 256, 0, stream>>>(termbuf, labels, mask, class_sum, class_cnt);
    k_final<<<1, 64, 0, stream>>>(class_sum, class_cnt, out);
}

// Round 5
// 354.220 us; speedup vs baseline: 1.2051x; 1.2051x over previous
//
#include <hip/hip_runtime.h>
#include <hip/hip_bf16.h>
#include <math.h>

#define B_ 4
#define F_ 256
#define H_ 64
#define W_ 64
#define C_ 19
#define S_ 256
#define N_ (B_*H_*W_)      // 16384 pixels
#define M_ (C_*2*S_)       // 9728 memory rows

typedef __bf16 bf16_t;
typedef bf16_t bf16x8 __attribute__((ext_vector_type(8)));
typedef float floatx4 __attribute__((ext_vector_type(4)));

#define ZERO_FLOATS (N_ + 2*C_)

// Fragment-order layout for A16/B16: element (row, f) lives at
//   ((row>>4)*8 + (f>>5))*512 + ((f>>3)&3)*128 + (row&15)*8 + (f&7)
// so a wave's MFMA fragment (16-row group g, 32-wide k-step kt) is the
// contiguous 1 KB at (g*8+kt)*512, in order lane*8 with lane=(kchunk<<4)|row.
__device__ inline size_t fragoff(int row, int f) {
    return ((size_t)((row >> 4) * 8 + (f >> 5))) * 512
         + (size_t)((((f >> 3) & 3) * 128) + ((row & 15) * 8) + (f & 7));
}

// ---------------- kernel 1: fused prep ----------------
__global__ __launch_bounds__(256) void k_prep(const float* __restrict__ pred,
                                              const float* __restrict__ mem,
                                              __hip_bfloat16* __restrict__ A16,
                                              __hip_bfloat16* __restrict__ B16,
                                              float* __restrict__ zero_base) {
    int bid = blockIdx.x;
    int t = threadIdx.x;
    if (bid < 256) {
        // ---- conv A: block = (b, hw-tile of 64); thread (q = t>>6, j = t&63)
        __shared__ float part[4][64];
        __shared__ float invf_s[64];
        int b = bid >> 6, hw0 = (bid & 63) * 64;
        int j = t & 63, q = t >> 6;
        const float* base = pred + ((size_t)b * F_ + q * 64) * 4096 + hw0 + j;
        float v[64];
        float s = 0.f;
        #pragma unroll
        for (int i = 0; i < 64; ++i) {
            float x = base[(size_t)i * 4096];
            v[i] = x;
            s += x * x;
        }
        part[q][j] = s;
        __syncthreads();
        if (t < 64) invf_s[t] = 1.0f / sqrtf(part[0][t] + part[1][t] + part[2][t] + part[3][t]);
        __syncthreads();
        float invf = invf_s[j];
        int n = b * 4096 + hw0 + j;
        #pragma unroll
        for (int c = 0; c < 8; ++c) {
            __hip_bfloat16 tmp[8];
            #pragma unroll
            for (int u = 0; u < 8; ++u) tmp[u] = __float2bfloat16(v[c * 8 + u] * invf);
            *(float4*)&A16[fragoff(n, q * 64 + c * 8)] = *(float4*)tmp;
        }
    } else if (bid < 256 + M_ / 4) {
        // ---- conv B: wave per memory row
        int row  = (bid - 256) * 4 + (t >> 6);
        int lane = t & 63;
        float4 a = ((const float4*)(mem + (size_t)row * F_))[lane];
        float s = a.x*a.x + a.y*a.y + a.z*a.z + a.w*a.w;
        #pragma unroll
        for (int off = 32; off; off >>= 1) s += __shfl_xor(s, off, 64);
        float invm = 1.0f / sqrtf(s);
        __hip_bfloat16 tmp[4];
        tmp[0] = __float2bfloat16(a.x * invm);
        tmp[1] = __float2bfloat16(a.y * invm);
        tmp[2] = __float2bfloat16(a.z * invm);
        tmp[3] = __float2bfloat16(a.w * invm);
        *(float2*)&B16[fragoff(row, lane * 4)] = *(float2*)tmp;
    } else {
        int idx = (bid - (256 + M_ / 4)) * 1024 + t * 4;
        #pragma unroll
        for (int u = 0; u < 4; ++u)
            if (idx + u < ZERO_FLOATS) zero_base[idx + u] = 0.f;
    }
}

// ---------------- kernel 2: MFMA cos->exp GEMM, register-direct, zero barriers ----
// grid = (M_/128=76, N_/128=128), block = 256 (4 waves), each wave a 64x64 quadrant.
// Fragments load straight from the pre-swizzled A16/B16 (L2/L3-resident) as
// fully-coalesced 1 KB global_load_dwordx4 per wave — no LDS, no __syncthreads
// in the K-loop; the unrolled loop exposes 64 independent loads for the
// scheduler to interleave with MFMAs (vmcnt(N) pipelining).
__global__ __launch_bounds__(256) void k_mfma(const __hip_bfloat16* __restrict__ A16,
                                              const __hip_bfloat16* __restrict__ B16,
                                              const int* __restrict__ labels,
                                              float* __restrict__ total,
                                              float* __restrict__ classbuf) {
    __shared__ int lab_s[128];
    int t = threadIdx.x;
    int w = t >> 6, lane = t & 63;
    int m0 = blockIdx.x * 128;
    int n0 = blockIdx.y * 128;
    if (t < 128) lab_s[t] = labels[n0 + t];
    __syncthreads();

    int nq = (w & 1) * 64, mq = (w >> 1) * 64;
    floatx4 acc[4][4];
    #pragma unroll
    for (int i = 0; i < 4; ++i)
        #pragma unroll
        for (int j = 0; j < 4; ++j) acc[i][j] = (floatx4){0.f, 0.f, 0.f, 0.f};

    // bf16x8-granular pointers: fragment (group g, kstep kt) = [(g*8+kt)*64 + lane]
    const bf16x8* Ap = (const bf16x8*)A16 + ((size_t)((n0 >> 4) + (w & 1) * 4) * 8) * 64 + lane;
    const bf16x8* Bp = (const bf16x8*)B16 + ((size_t)((m0 >> 4) + (w >> 1) * 4) * 8) * 64 + lane;

    #pragma unroll
    for (int kt = 0; kt < 8; ++kt) {
        bf16x8 af[4], bfr[4];
        #pragma unroll
        for (int ni = 0; ni < 4; ++ni) af[ni]  = Ap[(size_t)(ni * 8 + kt) * 64];
        #pragma unroll
        for (int mi = 0; mi < 4; ++mi) bfr[mi] = Bp[(size_t)(mi * 8 + kt) * 64];
        #pragma unroll
        for (int ni = 0; ni < 4; ++ni)
            #pragma unroll
            for (int mi = 0; mi < 4; ++mi)
                acc[ni][mi] = __builtin_amdgcn_mfma_f32_16x16x32_bf16(af[ni], bfr[mi], acc[ni][mi], 0, 0, 0);
    }

    // epilogue: E = exp(2*cos); row sums -> total (atomic); own-class scatter
    int cls   = m0 >> 9;
    int mbase = (m0 & 511) + mq;
    int colL  = lane & 15;
    int rgrp  = (lane >> 4) * 4;
    #pragma unroll
    for (int ni = 0; ni < 4; ++ni) {
        float Ev[4][4];
        float rsum[4] = {0.f, 0.f, 0.f, 0.f};
        #pragma unroll
        for (int mi = 0; mi < 4; ++mi)
            #pragma unroll
            for (int r = 0; r < 4; ++r) {
                float e = __expf(2.0f * acc[ni][mi][r]);
                Ev[mi][r] = e;
                rsum[r] += e;
            }
        #pragma unroll
        for (int r = 0; r < 4; ++r) {
            float s = rsum[r];
            s += __shfl_xor(s, 1, 64);
            s += __shfl_xor(s, 2, 64);
            s += __shfl_xor(s, 4, 64);
            s += __shfl_xor(s, 8, 64);
            int nrow = nq + ni * 16 + rgrp + r;
            if (colL == 0) atomicAdd(&total[n0 + nrow], s);
            if (lab_s[nrow] == cls) {
                size_t base = (size_t)(n0 + nrow) * 512 + mbase;
                #pragma unroll
                for (int mi = 0; mi < 4; ++mi)
                    classbuf[base + mi * 16 + colL] = Ev[mi][r];
            }
        }
    }
}

// ---------------- kernel 3: per-pixel log terms -> termbuf (no atomics) ----------------
__global__ __launch_bounds__(256) void k_terms(const float* __restrict__ classbuf,
                                               const float* __restrict__ total,
                                               const int*   __restrict__ mask,
                                               const int*   __restrict__ wmem,
                                               float* __restrict__ termbuf) {
    int wid  = threadIdx.x >> 6;
    int lane = threadIdx.x & 63;
    int n = blockIdx.x * 4 + wid;
    if (!mask[n]) {
        if (lane == 0) termbuf[n] = 0.f;
        return;
    }
    int wm = wmem[n];
    const float4* p = (const float4*)&classbuf[(size_t)n * 512];
    float4 v0 = p[lane * 2];
    float4 v1 = p[lane * 2 + 1];
    float s = v0.x + v0.y + v0.z + v0.w + v1.x + v1.y + v1.z + v1.w;
    #pragma unroll
    for (int off = 1; off < 64; off <<= 1) s += __shfl_xor(s, off, 64);
    float down = total[n] - s;
    int lo = (wm == 1) ? 0 : 32;                // wm==1 -> first half [0,S)
    float ts = 0.f;
    if (lane >= lo && lane < lo + 32) {
        float vv[8] = {v0.x, v0.y, v0.z, v0.w, v1.x, v1.y, v1.z, v1.w};
        #pragma unroll
        for (int q = 0; q < 8; ++q) {
            float pv = vv[q];
            ts += -logf(pv / (pv + down + 1e-12f) + 1e-12f);
        }
    }
    #pragma unroll
    for (int off = 1; off < 64; off <<= 1) ts += __shfl_xor(ts, off, 64);
    if (lane == 0) termbuf[n] = ts;
}

// ---------------- kernel 4: per-class reduction (block per class, no atomics) ----
__global__ __launch_bounds__(256) void k_reduce(const float* __restrict__ termbuf,
                                                const int*   __restrict__ labels,
                                                const int*   __restrict__ mask,
                                                float* __restrict__ class_sum,
                                                int*   __restrict__ class_cnt) {
    int c = blockIdx.x;
    int t = threadIdx.x;
    float s = 0.f;
    int cnt = 0;
    for (int n = t; n < N_; n += 256) {
        bool sel = mask[n] && (labels[n] == c);
        if (sel) { s += termbuf[n]; ++cnt; }
    }
    __shared__ float sred[256];
    __shared__ int   cred[256];
    sred[t] = s; cred[t] = cnt;
    __syncthreads();
    #pragma unroll
    for (int off = 128; off; off >>= 1) {
        if (t < off) { sred[t] += sred[t + off]; cred[t] += cred[t + off]; }
        __syncthreads();
    }
    if (t == 0) { class_sum[c] = sred[0]; class_cnt[c] = cred[0]; }
}

// ---------------- kernel 5: final class average ----------------
__global__ void k_final(const float* __restrict__ class_sum,
                        const int*   __restrict__ class_cnt,
                        float* __restrict__ out) {
    if (threadIdx.x == 0 && blockIdx.x == 0) {
        float loss = 0.f, kc = 0.f;
        for (int c = 0; c < C_; ++c) {
            int cnt = class_cnt[c];
            if (cnt > 0) {
                loss += class_sum[c] / ((float)cnt * (float)S_);
                kc += 1.f;
            }
        }
        out[0] = loss / fmaxf(kc, 1.f);
    }
}

extern "C" void kernel_launch(void* const* d_in, const int* in_sizes, int n_in,
                              void* d_out, int out_size, void* d_ws, size_t ws_size,
                              hipStream_t stream) {
    const float* mem    = (const float*)d_in[0];
    const float* pred   = (const float*)d_in[1];
    const int*   labels = (const int*)  d_in[2];
    const int*   mask   = (const int*)  d_in[3];
    const int*   wmem   = (const int*)  d_in[4];
    float* out = (float*)d_out;

    float* ws        = (float*)d_ws;
    float* total     = ws;                        // N_ floats (zeroed by k_prep)
    float* class_sum = ws + N_;                   // C_ floats
    int*   class_cnt = (int*)(ws + N_ + C_);      // C_ ints
    float* termbuf   = ws + 16432;                // N_ floats
    float* classbuf  = ws + 32816;                // N_*512 floats = 33.5 MB (16B aligned)
    __hip_bfloat16* A16 = (__hip_bfloat16*)(ws + 32816 + (size_t)N_ * 512);            // 8 MB
    __hip_bfloat16* B16 = (__hip_bfloat16*)(ws + 32816 + (size_t)N_ * 512 + 2097152);  // 4.75 MB

    k_prep<<<256 + M_ / 4 + 17, 256, 0, stream>>>(pred, mem, A16, B16, ws);

    dim3 g2(M_ / 128, N_ / 128);
    k_mfma<<<g2, 256, 0, stream>>>(A16, B16, labels, total, classbuf);

    k_terms<<<N_ / 4, 256, 0, stream>>>(classbuf, total, mask, wmem, termbuf);
    k_reduce<<<C_, 256, 0, stream>>>(termbuf, labels, mask, class_sum, class_cnt);
    k_final<<<1, 64, 0, stream>>>(class_sum, class_cnt, out);
}

// Round 6
// 335.056 us; speedup vs baseline: 1.2740x; 1.0572x over previous
//
#include <hip/hip_runtime.h>
#include <hip/hip_bf16.h>
#include <math.h>

#define B_ 4
#define F_ 256
#define C_ 19
#define S_ 256
#define N_ 16384
#define M_ 9728

typedef __bf16 bf16_t;
typedef bf16_t bf16x8 __attribute__((ext_vector_type(8)));
typedef float floatx4 __attribute__((ext_vector_type(4)));

// Fragment-order layout: element (row, f) lives at
//   ((row>>4)*8 + (f>>5))*512 + ((f>>3)&3)*128 + (row&15)*8 + (f&7)
// so fragment (16-row group g, 32-wide k-step kt) is the contiguous 1 KB at
// (g*8+kt)*512, in order lane*8 with lane=(kchunk<<4)|row.  (validated r5)
__device__ inline size_t fragoff(int row, int f) {
    return ((size_t)((row >> 4) * 8 + (f >> 5))) * 512
         + (size_t)((((f >> 3) & 3) * 128) + ((row & 15) * 8) + (f & 7));
}

// ---------------- kernel 1: normalize mem -> B16 (fragment order) ----------------
__global__ __launch_bounds__(256) void k_prepB(const float* __restrict__ mem,
                                               __hip_bfloat16* __restrict__ B16) {
    int row  = blockIdx.x * 4 + (threadIdx.x >> 6);
    int lane = threadIdx.x & 63;
    float4 a = ((const float4*)(mem + (size_t)row * F_))[lane];
    float s = a.x*a.x + a.y*a.y + a.z*a.z + a.w*a.w;
    #pragma unroll
    for (int off = 32; off; off >>= 1) s += __shfl_xor(s, off, 64);
    float invm = 1.0f / sqrtf(s);
    __hip_bfloat16 tmp[4];
    tmp[0] = __float2bfloat16(a.x * invm);
    tmp[1] = __float2bfloat16(a.y * invm);
    tmp[2] = __float2bfloat16(a.z * invm);
    tmp[3] = __float2bfloat16(a.w * invm);
    *(float2*)&B16[fragoff(row, lane * 4)] = *(float2*)tmp;
}

// ---------------- kernel 2: persistent n-panel GEMM + fused terms ----------------
// grid = 256 blocks (one per 64-pixel panel, 1/CU), 512 threads = 8 waves (2/SIMD).
// Per class-iteration the 8 waves m-split the class's 512 columns (wave ws gets
// cols [ws*64, ws*64+64)).  A panel staged once in LDS (fragment order, broadcast
// reads).  B fragments register-direct from L2-hot pre-swizzled B16.  total[]
// accumulates in registers; class-block E values -> bf16 Ebuf; terms fused at tail.
__global__ __launch_bounds__(512, 2) void k_main(const float* __restrict__ pred,
                                                 const __hip_bfloat16* __restrict__ B16,
                                                 const int* __restrict__ labels,
                                                 const int* __restrict__ mask,
                                                 const int* __restrict__ wmem,
                                                 __hip_bfloat16* __restrict__ Ebuf,
                                                 float* __restrict__ termbuf) {
    __shared__ __hip_bfloat16 As[64 * 256];   // 32 KB, fragment order
    __shared__ float part[512];
    __shared__ float invf_s[64];
    __shared__ float totals_s[8][64];
    __shared__ float total_s[64];
    __shared__ int   lab_s[64];

    int t = threadIdx.x, ws = t >> 6, lane = t & 63;
    int n0 = blockIdx.x * 64;
    int b = n0 >> 12, hw0 = n0 & 4095;

    // ---- phase A: load 64-pixel slice of pred, norms, bf16 -> LDS fragment order
    {
        int j  = lane;          // pixel within panel
        int fc = ws * 32;       // this wave's f-chunk
        const float* pp = pred + ((size_t)(b * F_ + fc)) * 4096 + hw0 + j;
        float v[32];
        float ss = 0.f;
        #pragma unroll
        for (int i = 0; i < 32; ++i) {
            float x = pp[(size_t)i * 4096];
            v[i] = x;
            ss += x * x;
        }
        part[t] = ss;
        if (t < 64) lab_s[t] = labels[n0 + t];
        __syncthreads();
        if (t < 64) {
            float s = 0.f;
            #pragma unroll
            for (int q = 0; q < 8; ++q) s += part[q * 64 + t];
            invf_s[t] = 1.0f / sqrtf(s);
        }
        __syncthreads();
        float invf = invf_s[j];
        #pragma unroll
        for (int c = 0; c < 4; ++c) {
            int f = fc + c * 8;
            __hip_bfloat16 tmp[8];
            #pragma unroll
            for (int u = 0; u < 8; ++u) tmp[u] = __float2bfloat16(v[c * 8 + u] * invf);
            int base = ((j >> 4) * 8 + (f >> 5)) * 512 + ((f >> 3) & 3) * 128 + (j & 15) * 8;
            *(float4*)&As[base] = *(float4*)tmp;
        }
        __syncthreads();
    }

    float racc[4][4];
    #pragma unroll
    for (int i = 0; i < 4; ++i)
        #pragma unroll
        for (int r = 0; r < 4; ++r) racc[i][r] = 0.f;
    int colL = lane & 15, rgrp = (lane >> 4) * 4;

    // ---- m-loop: one iteration per class (512 columns)
    for (int it = 0; it < C_; ++it) {
        int mg0 = it * 32 + ws * 4;                 // first 16-row m-group of this wave
        const bf16x8* Bp = (const bf16x8*)B16 + (size_t)mg0 * 8 * 64 + lane;
        floatx4 acc[4][4];
        #pragma unroll
        for (int i = 0; i < 4; ++i)
            #pragma unroll
            for (int j2 = 0; j2 < 4; ++j2) acc[i][j2] = (floatx4){0.f, 0.f, 0.f, 0.f};

        #pragma unroll
        for (int kt = 0; kt < 8; ++kt) {
            bf16x8 af[4], bfr[4];
            #pragma unroll
            for (int ni = 0; ni < 4; ++ni)
                af[ni] = *(const bf16x8*)&As[(ni * 8 + kt) * 512 + lane * 8];
            #pragma unroll
            for (int mi = 0; mi < 4; ++mi)
                bfr[mi] = Bp[(size_t)(mi * 8 + kt) * 64];
            #pragma unroll
            for (int ni = 0; ni < 4; ++ni)
                #pragma unroll
                for (int mi = 0; mi < 4; ++mi)
                    acc[ni][mi] = __builtin_amdgcn_mfma_f32_16x16x32_bf16(af[ni], bfr[mi], acc[ni][mi], 0, 0, 0);
        }

        // epilogue: E = exp(2*cos); accumulate row totals; own-class scatter (bf16)
        #pragma unroll
        for (int ni = 0; ni < 4; ++ni) {
            #pragma unroll
            for (int r = 0; r < 4; ++r) {
                int nrow = ni * 16 + rgrp + r;
                bool sel = (lab_s[nrow] == it);
                size_t ebase = (size_t)(n0 + nrow) * 512 + ws * 64 + colL;
                #pragma unroll
                for (int mi = 0; mi < 4; ++mi) {
                    float e = __expf(2.0f * acc[ni][mi][r]);
                    racc[ni][r] += e;
                    if (sel) Ebuf[ebase + mi * 16] = __float2bfloat16(e);
                }
            }
        }
    }

    // ---- combine row totals across the 16 colL lanes, then across the 8 waves
    #pragma unroll
    for (int ni = 0; ni < 4; ++ni)
        #pragma unroll
        for (int r = 0; r < 4; ++r) {
            float s = racc[ni][r];
            s += __shfl_xor(s, 1, 64);
            s += __shfl_xor(s, 2, 64);
            s += __shfl_xor(s, 4, 64);
            s += __shfl_xor(s, 8, 64);
            if (colL == 0) totals_s[ws][ni * 16 + rgrp + r] = s;
        }
    __syncthreads();
    if (t < 64) {
        float s = 0.f;
        #pragma unroll
        for (int w2 = 0; w2 < 8; ++w2) s += totals_s[w2][t];
        total_s[t] = s;
    }
    __syncthreads();

    // ---- fused per-pixel log terms: wave ws handles pixels [ws*8, ws*8+8)
    for (int q = 0; q < 8; ++q) {
        int nl = ws * 8 + q;
        int n  = n0 + nl;
        if (!mask[n]) {
            if (lane == 0) termbuf[n] = 0.f;
            continue;
        }
        int wm = wmem[n];
        bf16x8 ev = *(const bf16x8*)&Ebuf[(size_t)n * 512 + lane * 8];
        float vv[8];
        #pragma unroll
        for (int u = 0; u < 8; ++u) vv[u] = (float)ev[u];
        float s = vv[0] + vv[1] + vv[2] + vv[3] + vv[4] + vv[5] + vv[6] + vv[7];
        #pragma unroll
        for (int off = 1; off < 64; off <<= 1) s += __shfl_xor(s, off, 64);
        float down = total_s[nl] - s;
        int lo = (wm == 1) ? 0 : 32;                // wm==1 -> first half [0,S)
        float ts = 0.f;
        if (lane >= lo && lane < lo + 32) {
            #pragma unroll
            for (int u = 0; u < 8; ++u) {
                float pv = vv[u];
                ts += -logf(pv / (pv + down + 1e-12f) + 1e-12f);
            }
        }
        #pragma unroll
        for (int off = 1; off < 64; off <<= 1) ts += __shfl_xor(ts, off, 64);
        if (lane == 0) termbuf[n] = ts;
    }
}

// ---------------- kernel 3: per-class reduction (block per class, no atomics) ----
__global__ __launch_bounds__(256) void k_reduce(const float* __restrict__ termbuf,
                                                const int*   __restrict__ labels,
                                                const int*   __restrict__ mask,
                                                float* __restrict__ class_sum,
                                                int*   __restrict__ class_cnt) {
    int c = blockIdx.x;
    int t = threadIdx.x;
    float s = 0.f;
    int cnt = 0;
    for (int n = t; n < N_; n += 256) {
        bool sel = mask[n] && (labels[n] == c);
        if (sel) { s += termbuf[n]; ++cnt; }
    }
    __shared__ float sred[256];
    __shared__ int   cred[256];
    sred[t] = s; cred[t] = cnt;
    __syncthreads();
    #pragma unroll
    for (int off = 128; off; off >>= 1) {
        if (t < off) { sred[t] += sred[t + off]; cred[t] += cred[t + off]; }
        __syncthreads();
    }
    if (t == 0) { class_sum[c] = sred[0]; class_cnt[c] = cred[0]; }
}

// ---------------- kernel 4: final class average ----------------
__global__ void k_final(const float* __restrict__ class_sum,
                        const int*   __restrict__ class_cnt,
                        float* __restrict__ out) {
    if (threadIdx.x == 0 && blockIdx.x == 0) {
        float loss = 0.f, kc = 0.f;
        for (int c = 0; c < C_; ++c) {
            int cnt = class_cnt[c];
            if (cnt > 0) {
                loss += class_sum[c] / ((float)cnt * (float)S_);
                kc += 1.f;
            }
        }
        out[0] = loss / fmaxf(kc, 1.f);
    }
}

extern "C" void kernel_launch(void* const* d_in, const int* in_sizes, int n_in,
                              void* d_out, int out_size, void* d_ws, size_t ws_size,
                              hipStream_t stream) {
    const float* mem    = (const float*)d_in[0];
    const float* pred   = (const float*)d_in[1];
    const int*   labels = (const int*)  d_in[2];
    const int*   mask   = (const int*)  d_in[3];
    const int*   wmem   = (const int*)  d_in[4];
    float* out = (float*)d_out;

    float* ws        = (float*)d_ws;
    float* termbuf   = ws;                        // N_ floats (fully written by k_main)
    float* class_sum = ws + N_;                   // C_ floats (written by k_reduce)
    int*   class_cnt = (int*)(ws + N_ + C_);      // C_ ints
    // Ebuf at float offset 16424 (16B aligned): N_*512 bf16 = 16.78 MB
    __hip_bfloat16* Ebuf = (__hip_bfloat16*)(ws + 16424);
    __hip_bfloat16* B16  = (__hip_bfloat16*)(ws + 16424) + (size_t)N_ * 512;  // 4.86 MB

    k_prepB<<<M_ / 4, 256, 0, stream>>>(mem, B16);
    k_main<<<N_ / 64, 512, 0, stream>>>(pred, B16, labels, mask, wmem, Ebuf, termbuf);
    k_reduce<<<C_, 256, 0, stream>>>(termbuf, labels, mask, class_sum, class_cnt);
    k_final<<<1, 64, 0, stream>>>(class_sum, class_cnt, out);
}

// Round 7
// 331.837 us; speedup vs baseline: 1.2864x; 1.0097x over previous
//
#include <hip/hip_runtime.h>
#include <hip/hip_bf16.h>
#include <math.h>

#define B_ 4
#define F_ 256
#define C_ 19
#define S_ 256
#define N_ 16384
#define M_ 9728
#define MH_ 152          // 76 m-blocks * 2 halves

typedef __bf16 bf16_t;
typedef bf16_t bf16x8 __attribute__((ext_vector_type(8)));
typedef float floatx4 __attribute__((ext_vector_type(4)));

// Fragment-order layout (validated r5/r6): element (row, f) lives at
//   ((row>>4)*8 + (f>>5))*512 + ((f>>3)&3)*128 + (row&15)*8 + (f&7)
// so fragment (16-row group g, 32-wide k-step kt) is the contiguous 1 KB at
// (g*8+kt)*512, ordered lane*8 with lane=(kchunk<<4)|row.
__device__ inline size_t fragoff(int row, int f) {
    return ((size_t)((row >> 4) * 8 + (f >> 5))) * 512
         + (size_t)((((f >> 3) & 3) * 128) + ((row & 15) * 8) + (f & 7));
}

// ---------------- kernel 1: fused prep ----------------
// blocks [0,256): pred -> A16f (frag order) + A16r (row-major), normalized bf16
// blocks [256, 256+M_/4): mem -> B16 (frag order), normalized bf16
__global__ __launch_bounds__(256) void k_prep(const float* __restrict__ pred,
                                              const float* __restrict__ mem,
                                              __hip_bfloat16* __restrict__ A16f,
                                              __hip_bfloat16* __restrict__ A16r,
                                              __hip_bfloat16* __restrict__ B16) {
    int bid = blockIdx.x;
    int t = threadIdx.x;
    if (bid < 256) {
        __shared__ float part[4][64];
        __shared__ float invf_s[64];
        int b = bid >> 6, hw0 = (bid & 63) * 64;
        int j = t & 63, q = t >> 6;
        const float* base = pred + ((size_t)b * F_ + q * 64) * 4096 + hw0 + j;
        float v[64];
        float s = 0.f;
        #pragma unroll
        for (int i = 0; i < 64; ++i) {
            float x = base[(size_t)i * 4096];
            v[i] = x;
            s += x * x;
        }
        part[q][j] = s;
        __syncthreads();
        if (t < 64) invf_s[t] = 1.0f / sqrtf(part[0][t] + part[1][t] + part[2][t] + part[3][t]);
        __syncthreads();
        float invf = invf_s[j];
        int n = b * 4096 + hw0 + j;
        #pragma unroll
        for (int c = 0; c < 8; ++c) {
            int f = q * 64 + c * 8;
            __hip_bfloat16 tmp[8];
            #pragma unroll
            for (int u = 0; u < 8; ++u) tmp[u] = __float2bfloat16(v[c * 8 + u] * invf);
            *(float4*)&A16f[fragoff(n, f)] = *(float4*)tmp;
            *(float4*)&A16r[(size_t)n * F_ + f] = *(float4*)tmp;
        }
    } else {
        int row  = (bid - 256) * 4 + (t >> 6);
        int lane = t & 63;
        float4 a = ((const float4*)(mem + (size_t)row * F_))[lane];
        float s = a.x*a.x + a.y*a.y + a.z*a.z + a.w*a.w;
        #pragma unroll
        for (int off = 32; off; off >>= 1) s += __shfl_xor(s, off, 64);
        float invm = 1.0f / sqrtf(s);
        __hip_bfloat16 tmp[4];
        tmp[0] = __float2bfloat16(a.x * invm);
        tmp[1] = __float2bfloat16(a.y * invm);
        tmp[2] = __float2bfloat16(a.z * invm);
        tmp[3] = __float2bfloat16(a.w * invm);
        *(float2*)&B16[fragoff(row, lane * 4)] = *(float2*)tmp;
    }
}

// ---------------- kernel 2: pass-1 row-sum GEMM (register-direct, no LDS) ----------
// grid = (76, 128), 256 thr = 4 waves, wave = 64x64 quadrant. Output: per-(m-half)
// partial row sums of E = exp(2*cos) into totpart[152][N_] (each slot written once).
__global__ __launch_bounds__(256) void k_pass1(const __hip_bfloat16* __restrict__ A16f,
                                               const __hip_bfloat16* __restrict__ B16,
                                               float* __restrict__ totpart) {
    int t = threadIdx.x;
    int w = t >> 6, lane = t & 63;
    int m0 = blockIdx.x * 128;
    int n0 = blockIdx.y * 128;

    floatx4 acc[4][4];
    #pragma unroll
    for (int i = 0; i < 4; ++i)
        #pragma unroll
        for (int j = 0; j < 4; ++j) acc[i][j] = (floatx4){0.f, 0.f, 0.f, 0.f};

    const bf16x8* Ap = (const bf16x8*)A16f + ((size_t)((n0 >> 4) + (w & 1) * 4) * 8) * 64 + lane;
    const bf16x8* Bp = (const bf16x8*)B16  + ((size_t)((m0 >> 4) + (w >> 1) * 4) * 8) * 64 + lane;

    #pragma unroll
    for (int kt = 0; kt < 8; ++kt) {
        bf16x8 af[4], bfr[4];
        #pragma unroll
        for (int ni = 0; ni < 4; ++ni) af[ni]  = Ap[(size_t)(ni * 8 + kt) * 64];
        #pragma unroll
        for (int mi = 0; mi < 4; ++mi) bfr[mi] = Bp[(size_t)(mi * 8 + kt) * 64];
        #pragma unroll
        for (int ni = 0; ni < 4; ++ni)
            #pragma unroll
            for (int mi = 0; mi < 4; ++mi)
                acc[ni][mi] = __builtin_amdgcn_mfma_f32_16x16x32_bf16(af[ni], bfr[mi], acc[ni][mi], 0, 0, 0);
    }

    int colL = lane & 15, rgrp = (lane >> 4) * 4;
    size_t mh = (size_t)(blockIdx.x * 2 + (w >> 1)) * N_;
    #pragma unroll
    for (int ni = 0; ni < 4; ++ni) {
        #pragma unroll
        for (int r = 0; r < 4; ++r) {
            float s = __expf(2.0f * acc[ni][0][r]) + __expf(2.0f * acc[ni][1][r])
                    + __expf(2.0f * acc[ni][2][r]) + __expf(2.0f * acc[ni][3][r]);
            s += __shfl_xor(s, 1, 64);
            s += __shfl_xor(s, 2, 64);
            s += __shfl_xor(s, 4, 64);
            s += __shfl_xor(s, 8, 64);
            if (colL == 0)
                totpart[mh + n0 + (w & 1) * 64 + ni * 16 + rgrp + r] = s;
        }
    }
}

// ---------------- kernel 3: total[n] = sum of 152 partials ----------------
__global__ __launch_bounds__(256) void k_total(const float* __restrict__ totpart,
                                               float* __restrict__ total) {
    int n = blockIdx.x * 256 + threadIdx.x;
    float s = 0.f;
    #pragma unroll 8
    for (int i = 0; i < MH_; ++i) s += totpart[(size_t)i * N_ + n];
    total[n] = s;
}

// ---------------- kernel 4: bucket masked pixels by label ----------------
__global__ __launch_bounds__(1024) void k_bucket(const int* __restrict__ labels,
                                                 const int* __restrict__ mask,
                                                 int* __restrict__ bucket_off,
                                                 int* __restrict__ pix) {
    __shared__ int hist[C_];
    __shared__ int base[C_ + 1];
    int t = threadIdx.x;
    if (t < C_) hist[t] = 0;
    __syncthreads();
    for (int n = t; n < N_; n += 1024)
        if (mask[n]) atomicAdd(&hist[labels[n]], 1);
    __syncthreads();
    if (t == 0) {
        int a = 0;
        for (int c = 0; c < C_; ++c) { base[c] = a; a += hist[c]; }
        base[C_] = a;
    }
    __syncthreads();
    if (t < C_ + 1) bucket_off[t] = base[t];
    if (t < C_) hist[t] = base[t];            // reuse as cursors
    __syncthreads();
    for (int n = t; n < N_; n += 1024)
        if (mask[n]) { int p = atomicAdd(&hist[labels[n]], 1); pix[p] = n; }
}

// ---------------- kernel 5: pass-2 own-class recompute + exact terms ----------------
// grid = 275 blocks (upper bound of class tiles), 512 thr = 8 waves; wave ws owns
// cols [c*512 + ws*64, +64). Waves 0-3 = first half (wm==1), 4-7 = second (wm==0).
__global__ __launch_bounds__(512) void k_pass2(const __hip_bfloat16* __restrict__ A16r,
                                               const __hip_bfloat16* __restrict__ B16,
                                               const int* __restrict__ bucket_off,
                                               const int* __restrict__ pix,
                                               const float* __restrict__ total,
                                               const int* __restrict__ wmem,
                                               float* __restrict__ termbuf) {
    __shared__ __hip_bfloat16 As[64 * 256];   // 32 KB, fragment order
    __shared__ int off_s[C_ + 1];
    __shared__ int pidx_s[64];
    __shared__ float tot_s[64];
    __shared__ int wm_s[64];
    __shared__ float bsum_s[8][64];
    __shared__ float wsum_s[8][64];
    __shared__ float down_s[64];

    int t = threadIdx.x, ws = t >> 6, lane = t & 63;
    if (t < C_ + 1) off_s[t] = bucket_off[t];
    __syncthreads();

    int c = -1, tile = 0, cnt = 0, off = 0, accum = 0;
    for (int cc = 0; cc < C_; ++cc) {
        int cc_cnt = off_s[cc + 1] - off_s[cc];
        int nt = (cc_cnt + 63) >> 6;
        if ((int)blockIdx.x < accum + nt) { c = cc; tile = blockIdx.x - accum; cnt = cc_cnt; off = off_s[cc]; break; }
        accum += nt;
    }
    if (c < 0) return;

    if (t < 64) {
        int i = tile * 64 + t;
        int p = pix[off + (i < cnt ? i : 0)];
        pidx_s[t] = p;
        tot_s[t]  = total[p];
        wm_s[t]   = wmem[p];
    }
    __syncthreads();

    // stage gathered A rows into LDS fragment order
    #pragma unroll
    for (int s2 = 0; s2 < 4; ++s2) {
        int g = t + 512 * s2;          // 0..2047: 64 rows x 32 16B-chunks
        int row = g >> 5, f = (g & 31) * 8;
        float4 v = *(const float4*)&A16r[(size_t)pidx_s[row] * F_ + f];
        *(float4*)&As[fragoff(row, f)] = v;
    }
    __syncthreads();

    floatx4 acc[4][4];
    #pragma unroll
    for (int i = 0; i < 4; ++i)
        #pragma unroll
        for (int j = 0; j < 4; ++j) acc[i][j] = (floatx4){0.f, 0.f, 0.f, 0.f};

    const bf16x8* Bp = (const bf16x8*)B16 + ((size_t)(c * 32 + ws * 4) * 8) * 64 + lane;
    #pragma unroll
    for (int kt = 0; kt < 8; ++kt) {
        bf16x8 af[4], bfr[4];
        #pragma unroll
        for (int ni = 0; ni < 4; ++ni)
            af[ni] = *(const bf16x8*)&As[(ni * 8 + kt) * 512 + lane * 8];
        #pragma unroll
        for (int mi = 0; mi < 4; ++mi) bfr[mi] = Bp[(size_t)(mi * 8 + kt) * 64];
        #pragma unroll
        for (int ni = 0; ni < 4; ++ni)
            #pragma unroll
            for (int mi = 0; mi < 4; ++mi)
                acc[ni][mi] = __builtin_amdgcn_mfma_f32_16x16x32_bf16(af[ni], bfr[mi], acc[ni][mi], 0, 0, 0);
    }

    int colL = lane & 15, rgrp = (lane >> 4) * 4;
    float Ev[4][4][4];   // [ni][mi][r]
    #pragma unroll
    for (int ni = 0; ni < 4; ++ni)
        #pragma unroll
        for (int mi = 0; mi < 4; ++mi)
            #pragma unroll
            for (int r = 0; r < 4; ++r)
                Ev[ni][mi][r] = __expf(2.0f * acc[ni][mi][r]);

    // block-sum per row (all 512 cols of the class)
    #pragma unroll
    for (int ni = 0; ni < 4; ++ni)
        #pragma unroll
        for (int r = 0; r < 4; ++r) {
            float s = Ev[ni][0][r] + Ev[ni][1][r] + Ev[ni][2][r] + Ev[ni][3][r];
            s += __shfl_xor(s, 1, 64);
            s += __shfl_xor(s, 2, 64);
            s += __shfl_xor(s, 4, 64);
            s += __shfl_xor(s, 8, 64);
            if (colL == 0) bsum_s[ws][ni * 16 + rgrp + r] = s;
        }
    __syncthreads();
    if (t < 64) {
        float bs = 0.f;
        #pragma unroll
        for (int w2 = 0; w2 < 8; ++w2) bs += bsum_s[w2][t];
        down_s[t] = tot_s[t] - bs;
    }
    __syncthreads();

    // exact per-element terms over the selected half
    #pragma unroll
    for (int ni = 0; ni < 4; ++ni)
        #pragma unroll
        for (int r = 0; r < 4; ++r) {
            int row = ni * 16 + rgrp + r;
            bool sel = (wm_s[row] == 1) ? (ws < 4) : (ws >= 4);
            float tt = 0.f;
            if (sel) {
                float dwn = down_s[row];
                #pragma unroll
                for (int mi = 0; mi < 4; ++mi) {
                    float pv = Ev[ni][mi][r];
                    tt += -logf(pv / (pv + dwn + 1e-12f) + 1e-12f);
                }
            }
            tt += __shfl_xor(tt, 1, 64);
            tt += __shfl_xor(tt, 2, 64);
            tt += __shfl_xor(tt, 4, 64);
            tt += __shfl_xor(tt, 8, 64);
            if (colL == 0) wsum_s[ws][row] = tt;
        }
    __syncthreads();
    if (t < 64) {
        int i = tile * 64 + t;
        if (i < cnt) {
            float s = 0.f;
            #pragma unroll
            for (int w2 = 0; w2 < 8; ++w2) s += wsum_s[w2][t];
            termbuf[pidx_s[t]] = s;
        }
    }
}

// ---------------- kernel 6: per-class reduction ----------------
__global__ __launch_bounds__(256) void k_reduce(const float* __restrict__ termbuf,
                                                const int*   __restrict__ labels,
                                                const int*   __restrict__ mask,
                                                float* __restrict__ class_sum,
                                                int*   __restrict__ class_cnt) {
    int c = blockIdx.x;
    int t = threadIdx.x;
    float s = 0.f;
    int cnt = 0;
    for (int n = t; n < N_; n += 256) {
        bool sel = mask[n] && (labels[n] == c);
        if (sel) { s += termbuf[n]; ++cnt; }
    }
    __shared__ float sred[256];
    __shared__ int   cred[256];
    sred[t] = s; cred[t] = cnt;
    __syncthreads();
    #pragma unroll
    for (int off = 128; off; off >>= 1) {
        if (t < off) { sred[t] += sred[t + off]; cred[t] += cred[t + off]; }
        __syncthreads();
    }
    if (t == 0) { class_sum[c] = sred[0]; class_cnt[c] = cred[0]; }
}

// ---------------- kernel 7: final class average ----------------
__global__ void k_final(const float* __restrict__ class_sum,
                        const int*   __restrict__ class_cnt,
                        float* __restrict__ out) {
    if (threadIdx.x == 0 && blockIdx.x == 0) {
        float loss = 0.f, kc = 0.f;
        for (int c = 0; c < C_; ++c) {
            int cnt = class_cnt[c];
            if (cnt > 0) {
                loss += class_sum[c] / ((float)cnt * (float)S_);
                kc += 1.f;
            }
        }
        out[0] = loss / fmaxf(kc, 1.f);
    }
}

extern "C" void kernel_launch(void* const* d_in, const int* in_sizes, int n_in,
                              void* d_out, int out_size, void* d_ws, size_t ws_size,
                              hipStream_t stream) {
    const float* mem    = (const float*)d_in[0];
    const float* pred   = (const float*)d_in[1];
    const int*   labels = (const int*)  d_in[2];
    const int*   mask   = (const int*)  d_in[3];
    const int*   wmem   = (const int*)  d_in[4];
    float* out = (float*)d_out;

    float* ws        = (float*)d_ws;
    float* total      = ws;                               // [0, 16384)
    float* termbuf    = ws + 16384;                       // [16384, 32768)
    float* class_sum  = ws + 32768;                       // 19
    int*   class_cnt  = (int*)(ws + 32787);               // 19
    int*   bucket_off = (int*)(ws + 32806);               // 20
    int*   pix        = (int*)(ws + 32832);               // N_ ints
    float* totpart    = ws + 49216;                       // 152*N_ = 2,490,368 floats
    __hip_bfloat16* A16f = (__hip_bfloat16*)(ws + 2539584);   // 8 MB (frag order)
    __hip_bfloat16* A16r = (__hip_bfloat16*)(ws + 4636736);   // 8 MB (row major)
    __hip_bfloat16* B16  = (__hip_bfloat16*)(ws + 6733888);   // 4.75 MB (frag order)

    k_prep<<<256 + M_ / 4, 256, 0, stream>>>(pred, mem, A16f, A16r, B16);
    k_bucket<<<1, 1024, 0, stream>>>(labels, mask, bucket_off, pix);

    dim3 g1(76, 128);
    k_pass1<<<g1, 256, 0, stream>>>(A16f, B16, totpart);
    k_total<<<N_ / 256, 256, 0, stream>>>(totpart, total);

    k_pass2<<<275, 512, 0, stream>>>(A16r, B16, bucket_off, pix, total, wmem, termbuf);
    k_reduce<<<C_, 256, 0, stream>>>(termbuf, labels, mask, class_sum, class_cnt);
    k_final<<<1, 64, 0, stream>>>(class_sum, class_cnt, out);
}

// Round 8
// 224.404 us; speedup vs baseline: 1.9022x; 1.4787x over previous
//
#include <hip/hip_runtime.h>
#include <hip/hip_bf16.h>
#include <math.h>

#define B_ 4
#define F_ 256
#define C_ 19
#define S_ 256
#define N_ 16384
#define M_ 9728
#define MH_ 76           // 38 m-blocks * 2 halves

typedef __bf16 bf16_t;
typedef bf16_t bf16x8 __attribute__((ext_vector_type(8)));
typedef float floatx4 __attribute__((ext_vector_type(4)));

#define AS1 __attribute__((address_space(1)))
#define AS3 __attribute__((address_space(3)))

// Fragment-order layout (validated r5-r7): element (row, f) lives at
//   ((row>>4)*8 + (f>>5))*512 + ((f>>3)&3)*128 + (row&15)*8 + (f&7)
// fragment (16-row group g, k-step kt) = contiguous 1 KB at (g*8+kt)*512,
// ordered lane*8 with lane=(kchunk<<4)|row.
__device__ inline size_t fragoff(int row, int f) {
    return ((size_t)((row >> 4) * 8 + (f >> 5))) * 512
         + (size_t)((((f >> 3) & 3) * 128) + ((row & 15) * 8) + (f & 7));
}

// ---------------- kernel 1: fused prep + bucketing ----------------
// blocks [0,256): pred -> A16f (frag order, normalized bf16) + bucket 64 pixels
// blocks [256, 256+M_/4): mem -> B16 (frag order, normalized bf16)
__global__ __launch_bounds__(256) void k_prep(const float* __restrict__ pred,
                                              const float* __restrict__ mem,
                                              const int* __restrict__ labels,
                                              const int* __restrict__ mask,
                                              __hip_bfloat16* __restrict__ A16f,
                                              __hip_bfloat16* __restrict__ B16,
                                              int* __restrict__ ccnt,
                                              int* __restrict__ pix) {
    int bid = blockIdx.x;
    int t = threadIdx.x;
    if (bid < 256) {
        __shared__ float part[4][64];
        __shared__ float invf_s[64];
        __shared__ int hist[C_], base_s[C_], cur[C_];
        int b = bid >> 6, hw0 = (bid & 63) * 64;
        int j = t & 63, q = t >> 6;
        int n0 = b * 4096 + hw0;

        if (t < C_) { hist[t] = 0; cur[t] = 0; }
        int myc = 0, mym = 0;
        if (t < 64) { myc = labels[n0 + t]; mym = mask[n0 + t]; }

        const float* base = pred + ((size_t)b * F_ + q * 64) * 4096 + hw0 + j;
        float v[64];
        float s = 0.f;
        #pragma unroll
        for (int i = 0; i < 64; ++i) {
            float x = base[(size_t)i * 4096];
            v[i] = x;
            s += x * x;
        }
        part[q][j] = s;
        __syncthreads();
        if (t < 64) invf_s[t] = 1.0f / sqrtf(part[0][t] + part[1][t] + part[2][t] + part[3][t]);
        if (t < 64 && mym) atomicAdd(&hist[myc], 1);
        __syncthreads();
        if (t < C_) base_s[t] = atomicAdd(&ccnt[t], hist[t]);
        float invf = invf_s[j];
        #pragma unroll
        for (int c = 0; c < 8; ++c) {
            int f = q * 64 + c * 8;
            __hip_bfloat16 tmp[8];
            #pragma unroll
            for (int u = 0; u < 8; ++u) tmp[u] = __float2bfloat16(v[c * 8 + u] * invf);
            *(float4*)&A16f[fragoff(n0 + j, f)] = *(float4*)tmp;
        }
        __syncthreads();
        if (t < 64 && mym) {
            int o = atomicAdd(&cur[myc], 1);
            pix[myc * N_ + base_s[myc] + o] = n0 + t;
        }
    } else {
        int row  = (bid - 256) * 4 + (t >> 6);
        int lane = t & 63;
        float4 a = ((const float4*)(mem + (size_t)row * F_))[lane];
        float s = a.x*a.x + a.y*a.y + a.z*a.z + a.w*a.w;
        #pragma unroll
        for (int off = 32; off; off >>= 1) s += __shfl_xor(s, off, 64);
        float invm = 1.0f / sqrtf(s);
        __hip_bfloat16 tmp[4];
        tmp[0] = __float2bfloat16(a.x * invm);
        tmp[1] = __float2bfloat16(a.y * invm);
        tmp[2] = __float2bfloat16(a.z * invm);
        tmp[3] = __float2bfloat16(a.w * invm);
        *(float2*)&B16[fragoff(row, lane * 4)] = *(float2*)tmp;
    }
}

// ---------------- kernel 2: pass-1 row-sum GEMM, 128x256 blocks ----------------
// grid (38, 128), 256 thr = 4 waves. Wave w: n-half nh=(w&1) (64 rows from LDS
// A panel), m-half mh=(w>>1) (128 cols, register-direct B).  acc 4x8.  A panel
// (64 KB, frag order = contiguous in A16f) staged once via global_load_lds.
__global__ __launch_bounds__(256, 2) void k_pass1(const __hip_bfloat16* __restrict__ A16f,
                                                  const __hip_bfloat16* __restrict__ B16,
                                                  float* __restrict__ totpart) {
    __shared__ __hip_bfloat16 As[128 * 256];   // 64 KB
    int t = threadIdx.x, w = t >> 6, lane = t & 63;
    int m0 = blockIdx.x * 256;
    int n0 = blockIdx.y * 128;
    int nh = w & 1, mh = w >> 1;

    // stage A panel: contiguous 64 KB; dst wave-uniform base, src per-lane +16B
    {
        const __hip_bfloat16* src = A16f + ((size_t)n0 << 8) + lane * 8;
        #pragma unroll
        for (int i = 0; i < 16; ++i)
            __builtin_amdgcn_global_load_lds(
                (const AS1 unsigned int*)(src + i * 2048 + w * 512),
                (AS3 unsigned int*)&As[i * 2048 + w * 512], 16, 0, 0);
    }
    __syncthreads();

    floatx4 acc[4][8];
    #pragma unroll
    for (int i = 0; i < 4; ++i)
        #pragma unroll
        for (int j = 0; j < 8; ++j) acc[i][j] = (floatx4){0.f, 0.f, 0.f, 0.f};

    const bf16x8* Bp = (const bf16x8*)B16 + ((size_t)((m0 >> 4) + mh * 8) * 8) * 64 + lane;

    #pragma unroll
    for (int kt = 0; kt < 8; ++kt) {
        bf16x8 af[4], bfr[8];
        #pragma unroll
        for (int ni = 0; ni < 4; ++ni)
            af[ni] = *(const bf16x8*)&As[((nh * 4 + ni) * 8 + kt) * 512 + lane * 8];
        #pragma unroll
        for (int mi = 0; mi < 8; ++mi)
            bfr[mi] = Bp[(size_t)(mi * 8 + kt) * 64];
        #pragma unroll
        for (int ni = 0; ni < 4; ++ni)
            #pragma unroll
            for (int mi = 0; mi < 8; ++mi)
                acc[ni][mi] = __builtin_amdgcn_mfma_f32_16x16x32_bf16(af[ni], bfr[mi], acc[ni][mi], 0, 0, 0);
    }

    // epilogue: E = exp(2*cos) folded into per-lane row accumulators
    float racc[4][4];
    #pragma unroll
    for (int ni = 0; ni < 4; ++ni)
        #pragma unroll
        for (int r = 0; r < 4; ++r) racc[ni][r] = 0.f;
    #pragma unroll
    for (int ni = 0; ni < 4; ++ni)
        #pragma unroll
        for (int mi = 0; mi < 8; ++mi)
            #pragma unroll
            for (int r = 0; r < 4; ++r)
                racc[ni][r] += __expf(2.0f * acc[ni][mi][r]);

    int colL = lane & 15, rgrp = (lane >> 4) * 4;
    size_t slot = (size_t)(blockIdx.x * 2 + mh) * N_;
    #pragma unroll
    for (int ni = 0; ni < 4; ++ni)
        #pragma unroll
        for (int r = 0; r < 4; ++r) {
            float s = racc[ni][r];
            s += __shfl_xor(s, 1, 64);
            s += __shfl_xor(s, 2, 64);
            s += __shfl_xor(s, 4, 64);
            s += __shfl_xor(s, 8, 64);
            if (colL == 0)
                totpart[slot + n0 + nh * 64 + ni * 16 + rgrp + r] = s;
        }
}

// ---------------- kernel 3: total[n] = sum of 76 partials ----------------
__global__ __launch_bounds__(256) void k_total(const float* __restrict__ totpart,
                                               float* __restrict__ total) {
    int n = blockIdx.x * 256 + threadIdx.x;
    float s = 0.f;
    #pragma unroll 4
    for (int i = 0; i < MH_; ++i) s += totpart[(size_t)i * N_ + n];
    total[n] = s;
}

// ---------------- kernel 4: pass-2 own-class recompute + exact terms ----------------
// grid (19, 16), 512 thr = 8 waves; block = (class c, 64-pixel tile).  Wave ws
// owns cols [c*512+ws*64, +64).  Terms written bucket-dense into termC.
__global__ __launch_bounds__(512) void k_pass2(const __hip_bfloat16* __restrict__ A16f,
                                               const __hip_bfloat16* __restrict__ B16,
                                               const int* __restrict__ ccnt,
                                               const int* __restrict__ pix,
                                               const float* __restrict__ total,
                                               const int* __restrict__ wmem,
                                               float* __restrict__ termC) {
    __shared__ __hip_bfloat16 As[64 * 256];   // 32 KB, fragment order
    __shared__ int pidx_s[64];
    __shared__ float tot_s[64];
    __shared__ int wm_s[64];
    __shared__ float bsum_s[8][64];
    __shared__ float wsum_s[8][64];
    __shared__ float down_s[64];

    int c = blockIdx.x, tile = blockIdx.y;
    int cnt = ccnt[c];
    if (tile * 64 >= cnt) return;
    int t = threadIdx.x, ws = t >> 6, lane = t & 63;

    if (t < 64) {
        int i = tile * 64 + t;
        int p = pix[c * N_ + (i < cnt ? i : 0)];
        pidx_s[t] = p;
        tot_s[t]  = total[p];
        wm_s[t]   = wmem[p];
    }
    __syncthreads();

    // gather A rows (frag-order chunks) into LDS fragment order
    #pragma unroll
    for (int s2 = 0; s2 < 4; ++s2) {
        int g = t + 512 * s2;          // 0..2047: 64 rows x 32 16B-chunks
        int row = g >> 5, f = (g & 31) * 8;
        float4 v = *(const float4*)&A16f[fragoff(pidx_s[row], f)];
        *(float4*)&As[fragoff(row, f)] = v;
    }
    __syncthreads();

    floatx4 acc[4][4];
    #pragma unroll
    for (int i = 0; i < 4; ++i)
        #pragma unroll
        for (int j = 0; j < 4; ++j) acc[i][j] = (floatx4){0.f, 0.f, 0.f, 0.f};

    const bf16x8* Bp = (const bf16x8*)B16 + ((size_t)(c * 32 + ws * 4) * 8) * 64 + lane;
    #pragma unroll
    for (int kt = 0; kt < 8; ++kt) {
        bf16x8 af[4], bfr[4];
        #pragma unroll
        for (int ni = 0; ni < 4; ++ni)
            af[ni] = *(const bf16x8*)&As[(ni * 8 + kt) * 512 + lane * 8];
        #pragma unroll
        for (int mi = 0; mi < 4; ++mi) bfr[mi] = Bp[(size_t)(mi * 8 + kt) * 64];
        #pragma unroll
        for (int ni = 0; ni < 4; ++ni)
            #pragma unroll
            for (int mi = 0; mi < 4; ++mi)
                acc[ni][mi] = __builtin_amdgcn_mfma_f32_16x16x32_bf16(af[ni], bfr[mi], acc[ni][mi], 0, 0, 0);
    }

    int colL = lane & 15, rgrp = (lane >> 4) * 4;
    float Ev[4][4][4];
    #pragma unroll
    for (int ni = 0; ni < 4; ++ni)
        #pragma unroll
        for (int mi = 0; mi < 4; ++mi)
            #pragma unroll
            for (int r = 0; r < 4; ++r)
                Ev[ni][mi][r] = __expf(2.0f * acc[ni][mi][r]);

    #pragma unroll
    for (int ni = 0; ni < 4; ++ni)
        #pragma unroll
        for (int r = 0; r < 4; ++r) {
            float s = Ev[ni][0][r] + Ev[ni][1][r] + Ev[ni][2][r] + Ev[ni][3][r];
            s += __shfl_xor(s, 1, 64);
            s += __shfl_xor(s, 2, 64);
            s += __shfl_xor(s, 4, 64);
            s += __shfl_xor(s, 8, 64);
            if (colL == 0) bsum_s[ws][ni * 16 + rgrp + r] = s;
        }
    __syncthreads();
    if (t < 64) {
        float bs = 0.f;
        #pragma unroll
        for (int w2 = 0; w2 < 8; ++w2) bs += bsum_s[w2][t];
        down_s[t] = tot_s[t] - bs;
    }
    __syncthreads();

    #pragma unroll
    for (int ni = 0; ni < 4; ++ni)
        #pragma unroll
        for (int r = 0; r < 4; ++r) {
            int row = ni * 16 + rgrp + r;
            bool sel = (wm_s[row] == 1) ? (ws < 4) : (ws >= 4);
            float tt = 0.f;
            if (sel) {
                float dwn = down_s[row];
                #pragma unroll
                for (int mi = 0; mi < 4; ++mi) {
                    float pv = Ev[ni][mi][r];
                    tt += -logf(pv / (pv + dwn + 1e-12f) + 1e-12f);
                }
            }
            tt += __shfl_xor(tt, 1, 64);
            tt += __shfl_xor(tt, 2, 64);
            tt += __shfl_xor(tt, 4, 64);
            tt += __shfl_xor(tt, 8, 64);
            if (colL == 0) wsum_s[ws][row] = tt;
        }
    __syncthreads();
    if (t < 64) {
        int i = tile * 64 + t;
        if (i < cnt) {
            float s = 0.f;
            #pragma unroll
            for (int w2 = 0; w2 < 8; ++w2) s += wsum_s[w2][t];
            termC[c * N_ + i] = s;
        }
    }
}

// ---------------- kernel 5: fused per-class reduce + final ----------------
__global__ __launch_bounds__(256) void k_fin(const float* __restrict__ termC,
                                             const int* __restrict__ ccnt,
                                             float* __restrict__ out) {
    __shared__ float red[256];
    int t = threadIdx.x;
    float loss = 0.f, kc = 0.f;
    for (int c = 0; c < C_; ++c) {
        int cnt = ccnt[c];
        float s = 0.f;
        for (int i = t; i < cnt; i += 256) s += termC[c * N_ + i];
        red[t] = s;
        __syncthreads();
        #pragma unroll
        for (int off = 128; off; off >>= 1) {
            if (t < off) red[t] += red[t + off];
            __syncthreads();
        }
        if (t == 0 && cnt > 0) {
            loss += red[0] / ((float)cnt * (float)S_);
            kc += 1.f;
        }
        __syncthreads();
    }
    if (t == 0) out[0] = loss / fmaxf(kc, 1.f);
}

extern "C" void kernel_launch(void* const* d_in, const int* in_sizes, int n_in,
                              void* d_out, int out_size, void* d_ws, size_t ws_size,
                              hipStream_t stream) {
    const float* mem    = (const float*)d_in[0];
    const float* pred   = (const float*)d_in[1];
    const int*   labels = (const int*)  d_in[2];
    const int*   mask   = (const int*)  d_in[3];
    const int*   wmem   = (const int*)  d_in[4];
    float* out = (float*)d_out;

    float* ws = (float*)d_ws;
    float* total   = ws;                              // N_ floats
    float* totpart = ws + 16384;                      // 76*N_ = 1,245,184 floats
    int*   ccnt    = (int*)(ws + 1261568);            // 19 ints (memset to 0)
    int*   pix     = (int*)(ws + 1261600);            // 19*N_ ints
    float* termC   = ws + 1572896;                    // 19*N_ floats
    __hip_bfloat16* A16f = (__hip_bfloat16*)(ws + 1884192);   // 8 MB (frag order)
    __hip_bfloat16* B16  = (__hip_bfloat16*)(ws + 3981344);   // 4.86 MB (frag order)

    hipMemsetAsync(ccnt, 0, C_ * sizeof(int), stream);

    k_prep<<<256 + M_ / 4, 256, 0, stream>>>(pred, mem, labels, mask,
                                             A16f, B16, ccnt, pix);

    dim3 g1(38, 128);
    k_pass1<<<g1, 256, 0, stream>>>(A16f, B16, totpart);
    k_total<<<N_ / 256, 256, 0, stream>>>(totpart, total);

    dim3 g2(C_, 16);
    k_pass2<<<g2, 512, 0, stream>>>(A16f, B16, ccnt, pix, total, wmem, termC);
    k_fin<<<1, 256, 0, stream>>>(termC, ccnt, out);
}